// Round 6
// baseline (136.792 us; speedup 1.0000x reference)
//
#include <hip/hip_runtime.h>

constexpr int S  = 256;
constexpr int NL = 17;
constexpr int L  = 19;   // start = 17, end = 18

// LDS slot -> vocab-state maps. Slot 9 holds the renorm scale (mx).
// fwd layout: slots 0-8 = {O, E_k,S_k} (sources for heavy dests O/B/S),
//             slots 10-17 = {B_k,I_k} pairs (sources for light dests E/I).
// bwd layout: slots 0-8 = {O, B_k,S_k}, slots 10-17 = {I_k,E_k} pairs.
__constant__ int c_sig[2][18] = {
  {0, 3,4, 7,8, 11,12, 15,16,  0, 1,2, 5,6, 9,10, 13,14},
  {0, 1,4, 5,8, 9,12, 13,16,   0, 2,3, 6,7, 10,11, 14,15},
};

// ---- scheduling kernel: perm = seq ids sorted by length, longest first ----
__global__ __launch_bounds__(256)
void sched_kernel(const int* __restrict__ lens, int* __restrict__ perm, int B)
{
    __shared__ int hist[256];
    __shared__ int scanbuf[256];
    const int t = threadIdx.x;
    hist[t] = 0;
    __syncthreads();
    for (int s = t; s < B; s += 256) atomicAdd(&hist[256 - lens[s]], 1); // bin 0 = len 256
    __syncthreads();
    const int v = hist[t];
    scanbuf[t] = v;
    __syncthreads();
    for (int d = 1; d < 256; d <<= 1) {
        const int add = (t >= d) ? scanbuf[t - d] : 0;
        __syncthreads();
        scanbuf[t] += add;
        __syncthreads();
    }
    hist[t] = scanbuf[t] - v;   // exclusive prefix = running offset
    __syncthreads();
    for (int s = t; s < B; s += 256) {
        const int pos = atomicAdd(&hist[256 - lens[s]], 1);
        perm[pos] = s;
    }
}

// ---- main kernel: one wave per sequence; half 0 fwd, half 1 bwd ----
// fwd: z <- E(el_t o z), z0 = E[:,start], t = 0..mid-2; then z *= el_{mid-1}.
// bwd: W <- E^T(el_t o W), W0 = E[end,:], t = len-1 .. mid.
// P = sum_s z[s]*W[s];  norm = m_f + m_b + log P.
__global__ __launch_bounds__(64)
void crf_fwd(const float* __restrict__ logits,
             const int*   __restrict__ labels,
             const int*   __restrict__ lens,
             const float* __restrict__ transition,
             const int*   __restrict__ perm,
             float* __restrict__ out, int totalElemM1)
{
    __shared__ float Tsh[L * L];
    __shared__ __align__(16) float pbuf[2][2][32];  // [half][parity][slots]
    __shared__ float ebuf[2][20];

    const int tid  = threadIdx.x;
    const int half = tid >> 5;    // 0 = fwd, 1 = bwd
    const int slot = tid & 31;
    const int b    = perm ? perm[blockIdx.x] : (int)blockIdx.x;

    for (int k = tid; k < L * L; k += 64) Tsh[k] = transition[k];
    if (slot == 9) { pbuf[half][0][9] = 1.0f; pbuf[half][1][9] = 1.0f; }
    __syncthreads();

    const bool emit  = (slot < 18) && (slot != 9);
    const int  d     = emit ? c_sig[half][slot] : 0;          // my vocab state
    const bool heavy = emit && ((slot < 9) ? ((slot & 1) == 0)
                                           : ((slot & 1) == (half ? 1 : 0)));
    const bool hvx   = heavy || (slot == 9);                   // slot 9 = mx duty
    const bool light = emit && !heavy;

    // coefficients
    float ch[9];
    #pragma unroll
    for (int j = 0; j < 9; ++j) {
        const int s = c_sig[half][j];
        ch[j] = heavy ? __expf(half ? Tsh[s * L + d] : Tsh[d * L + s]) : 0.0f;
    }
    int kty = 0;
    if (light) kty = (slot < 9) ? ((slot - 1) >> 1) : ((slot - 10 - (half ? 0 : 1)) >> 1);
    const int pairSlot = 10 + 2 * kty;
    float cl0 = 0.0f, cl1 = 0.0f;
    if (light) {
        const int s0 = c_sig[half][pairSlot], s1 = c_sig[half][pairSlot + 1];
        cl0 = __expf(half ? Tsh[s0 * L + d] : Tsh[d * L + s0]);
        cl1 = __expf(half ? Tsh[s1 * L + d] : Tsh[d * L + s1]);
    }

    const int len = lens[b];
    const int mid = (len + 1) >> 1;
    const int nf  = mid - 1;          // fwd matvec steps
    const int nb  = len >> 1;         // bwd matvec steps (= len - mid), nb >= nf
    const int nup = half ? nb : nf;
    const int nsteps = (nb + 7) & ~7;

    const int seqbase = b * (S * NL);

    // init state
    float p = emit ? __expf(half ? Tsh[(L - 1) * L + d]      // E[end, d]
                                 : Tsh[d * L + (L - 2)])     // E[d, start]
                   : 0.0f;
    float m = 0.0f;

    // depth-8 prefetch: 32-bit byte offsets, per-lane caps
    const char* lgbase = (const char*)logits;
    const int capHiF = 4 * min(seqbase + (S - 1) * NL + d, totalElemM1);
    const int capHi  = half ? 0x7ffffffc : capHiF;
    const int capLo  = half ? 4 * seqbase : 0;
    const int stride = half ? -(8 * NL * 4) : (8 * NL * 4);

    int   off[8];
    float lgbuf[8];
    #pragma unroll
    for (int u = 0; u < 8; ++u) {
        int tok = half ? (len - 1 - u) : u;
        tok = tok > 0 ? tok : 0;
        int o = 4 * (seqbase + tok * NL + d);
        o = min(o, capHiF);
        off[u] = o;
        lgbuf[u] = *(const float*)(lgbase + o);
    }

    for (int tb = 0; tb < nsteps; tb += 8) {
        #pragma unroll
        for (int u = 0; u < 8; ++u) {
            const int   t  = tb + u;
            const float lg = lgbuf[u];
            int o = off[u] + stride;
            o = max(o, capLo);
            o = min(o, capHi);
            off[u] = o;
            lgbuf[u] = *(const float*)(lgbase + o);

            const bool upd = (t < nup);
            const float el = emit ? __expf(lg) : 0.0f;
            const float pe = p * el;

            float* pb = &pbuf[half][u & 1][0];
            if (emit) pb[slot] = pe;
            asm volatile("" ::: "memory");   // program-order pin; DS pipe is in-order per wave

            float v = 0.0f, mxv = 1.0f;
            if (hvx) {
                const float4 q0 = *(const float4*)(pb);
                const float4 q1 = *(const float4*)(pb + 4);
                const float2 q2 = *(const float2*)(pb + 8);   // (p8, mx)
                float a0 = q0.x * ch[0];
                float a1 = q0.y * ch[1];
                float a2 = q0.z * ch[2];
                a0 = fmaf(q0.w, ch[3], a0);
                a1 = fmaf(q1.x, ch[4], a1);
                a2 = fmaf(q1.y, ch[5], a2);
                a0 = fmaf(q1.z, ch[6], a0);
                a1 = fmaf(q1.w, ch[7], a1);
                a2 = fmaf(q2.x, ch[8], a2);
                v = (a0 + a1) + a2;
                mxv = q2.y;
                if ((u & 3) == 2 && slot == 9) {   // mx duty lane, feeds renorm at u+1
                    float m0 = fmaxf(fmaxf(q0.x, q0.y), fmaxf(q0.z, q0.w));
                    float m1 = fmaxf(fmaxf(q1.x, q1.y), fmaxf(q1.z, q1.w));
                    pbuf[half][1][9] = fmaxf(fmaxf(m0, m1), q2.x);
                }
            } else {
                const float2 pr = *(const float2*)(pb + pairSlot);
                v = pr.x * cl0;
                v = fmaf(pr.y, cl1, v);
                if ((u & 3) == 3) mxv = pb[9];
            }

            float pn = v;
            if ((u & 3) == 3) {
                pn *= __frcp_rn(mxv);
                m += upd ? __logf(mxv) : 0.0f;
            }
            p = upd ? pn : p;
        }
    }

    // fwd leftover: elementwise el of token mid-1
    if (!half && emit) {
        const float lgf = logits[(size_t)(seqbase + (mid - 1) * NL + d)];
        p *= __expf(lgf);
    }

    // combine in vocab order
    if (emit) ebuf[half][d] = p;
    asm volatile("" ::: "memory");
    float prod = 0.0f;
    if (slot < NL) prod = ebuf[0][slot] * ebuf[1][slot];
    #pragma unroll
    for (int o2 = 16; o2 >= 1; o2 >>= 1) prod += __shfl_xor(prod, o2, 32);
    const float mtot = m + __shfl_xor(m, 32);
    const float norm = mtot + __logf(prod);

    // gold path score: all 64 lanes sweep tokens
    const int* labp = labels + b * S;
    const int  wtid = tid;
    float gsum = 0.0f;
    for (int c = 0; c < len; c += 64) {
        const int tok = c + wtid;
        if (tok < len) {
            const int lab = labp[tok];
            const int prv = (tok == 0) ? (L - 2) : labp[tok - 1];
            gsum += logits[(size_t)(seqbase + tok * NL + lab)] + Tsh[lab * L + prv];
        }
    }
    #pragma unroll
    for (int o2 = 32; o2 >= 1; o2 >>= 1) gsum += __shfl_xor(gsum, o2);
    const float gold = gsum + Tsh[(L - 1) * L + labp[len - 1]];

    if (wtid == 0) out[b] = gold - norm;
}

extern "C" void kernel_launch(void* const* d_in, const int* in_sizes, int n_in,
                              void* d_out, int out_size, void* d_ws, size_t ws_size,
                              hipStream_t stream)
{
    (void)n_in; (void)out_size;
    const float* logits     = (const float*)d_in[0];
    const int*   labels     = (const int*)d_in[1];
    const int*   lens       = (const int*)d_in[2];
    const float* transition = (const float*)d_in[3];
    float*       out        = (float*)d_out;
    const int B = in_sizes[2];
    const int totalElemM1 = B * S * NL - 1;

    int* perm = nullptr;
    if (ws_size >= (size_t)B * sizeof(int)) {
        perm = (int*)d_ws;
        sched_kernel<<<dim3(1), dim3(256), 0, stream>>>(lens, perm, B);
    }
    crf_fwd<<<dim3(B), dim3(64), 0, stream>>>(
        logits, labels, lens, transition, perm, out, totalElemM1);
}